// Round 5
// baseline (378.015 us; speedup 1.0000x reference)
//
#include <hip/hip_runtime.h>
#include <hip/hip_bf16.h>

// Problem constants
#define BATCH 32
#define NSEQ  16384
#define DDIM  65
#define CHUNK 64
#define KQ    64
#define NBLK  256          // NSEQ / CHUNK
#define SCALE 0.12403473458920847f   // 65^-0.5

typedef __bf16 bf16x8 __attribute__((ext_vector_type(8)));
typedef float  f32x4  __attribute__((ext_vector_type(4)));
#define MFMA16(a, b, c) __builtin_amdgcn_mfma_f32_16x16x32_bf16(a, b, c, 0, 0, 0)

// blk layout: [(b*NBLK + nb)*64 + k] * 72 + d   (72-padded rows, 144 B,
// 16-B aligned; cols 65..71 are zeros).  Writer-contiguous per k_attn block.
#define BLK_ROWSTRIDE 72
#define BLK_CHUNKSTRIDE (64 * 72)              // per nb
#define BLK_BSTRIDE ((size_t)NBLK * 64 * 72)   // per b

__device__ __forceinline__ float gelu_exact(float v) {
    return 0.5f * v * (1.0f + erff(v * 0.7071067811865476f));
}

// tanh-approx GELU: |err| <= ~2e-4, far below bf16 rounding of keys/vals.
__device__ __forceinline__ float gelu_tanh(float x) {
    float x2 = x * x;
    float t  = 0.7978845608028654f * x * fmaf(0.044715f, x2, 1.0f);
    float e  = __expf(2.0f * t);
    float th = 1.0f - 2.0f * __builtin_amdgcn_rcpf(e + 1.0f);
    return 0.5f * x * (1.0f + th);
}

// ---------------------------------------------------------------------------
// Kernel 1: per-slice partial sums over N, float4 loads (4 rows = 65 aligned
// float4s; element e of float4 j has d = (4j+e) mod 65).  grid (32, 33):
// y==32 branch does the Wk/Wv transpose prep (32 blocks x 320 = 10240 elems).
// partial[(b*32+s)*65 + d]
// ---------------------------------------------------------------------------
__global__ __launch_bounds__(320) void k_gavg(const float* __restrict__ x,
                                              float* __restrict__ partial,
                                              const float* __restrict__ Wk,
                                              const float* __restrict__ Wv,
                                              __bf16* __restrict__ WkT,
                                              __bf16* __restrict__ WvT) {
    const int tid = threadIdx.x;
    if (blockIdx.y == 32) {                    // prep branch
        const int i = blockIdx.x * 320 + tid;  // 0 .. 10239
        const int m = i / 5120;
        const int j = i - m * 5120;
        const int d = j >> 6, e = j & 63;
        const float* W = m ? Wv : Wk;
        __bf16* T = m ? WvT : WkT;
        T[(size_t)d * 64 + e] = (d < DDIM) ? (__bf16)W[e * DDIM + d]
                                           : (__bf16)0.0f;
        return;
    }
    const int s = blockIdx.x;                  // 0..31, 512 rows each
    const int b = blockIdx.y;
    // 260 active threads: g = t/65 (4-row group within 16-row stripe), j fixed
    const int g = tid / 65;
    const int j = tid - g * 65;
    const bool active = tid < 260;
    float acc[4] = {0.f, 0.f, 0.f, 0.f};
    if (active) {
        const float4* p = (const float4*)(x + (size_t)b * NSEQ * DDIM
                                            + (size_t)s * 512 * DDIM);
        #pragma unroll 8
        for (int it = 0; it < 32; ++it) {      // 16 rows per iter
            const float4 v = p[(it * 4 + g) * 65 + j];
            acc[0] += v.x; acc[1] += v.y; acc[2] += v.z; acc[3] += v.w;
        }
    }
    __shared__ float lds[4][65][4];
    if (active) {
        lds[g][j][0] = acc[0]; lds[g][j][1] = acc[1];
        lds[g][j][2] = acc[2]; lds[g][j][3] = acc[3];
    }
    __syncthreads();
    if (tid < DDIM) {
        float a = 0.f;
        #pragma unroll
        for (int rr = 0; rr < 4; ++rr) {
            const int f = tid + 65 * rr;       // flat idx with d == tid
            const int jj = f >> 2, ee = f & 3;
            a += lds[0][jj][ee] + lds[1][jj][ee]
               + lds[2][jj][ee] + lds[3][jj][ee];
        }
        partial[((size_t)b * 32 + s) * DDIM + tid] = a;
    }
}

// ---------------------------------------------------------------------------
// Kernel 2a: reduce partials -> gavg; h = gelu(gavg@Wq1+bq1); r = gavg@Wr+br.
// ---------------------------------------------------------------------------
__global__ __launch_bounds__(256) void k_qgen1(const float* __restrict__ partial,
    const float* __restrict__ Wq1, const float* __restrict__ bq1,
    const float* __restrict__ Wr,  const float* __restrict__ br,
    float* __restrict__ h_out, float* __restrict__ r_out) {
    const int b = blockIdx.x, tid = threadIdx.x;
    __shared__ float g[DDIM];
    if (tid < DDIM) {
        float a = 0.f;
        const float* p = partial + (size_t)b * 32 * DDIM + tid;
        #pragma unroll 8
        for (int s = 0; s < 32; ++s) a += p[s * DDIM];
        g[tid] = a * (1.0f / 16384.0f);
    }
    __syncthreads();
    if (tid < DDIM) {
        float a = bq1[tid];
        for (int e = 0; e < DDIM; ++e) a += g[e] * Wq1[e * DDIM + tid];
        h_out[b * DDIM + tid] = gelu_exact(a);
    } else if (tid >= 128 && tid < 128 + DDIM) {
        const int d = tid - 128;
        float a = br[d];
        for (int e = 0; e < DDIM; ++e) a += g[e] * Wr[e * DDIM + d];
        r_out[b * DDIM + d] = a;
    }
}

// ---------------------------------------------------------------------------
// Kernel 2b: q = (h@Wq2+bq2)*SCALE -> qbf [64][64] bf16 + q64 col.
// ---------------------------------------------------------------------------
__global__ __launch_bounds__(256) void k_qgen2(const float* __restrict__ h_in,
    const float* __restrict__ Wq2, const float* __restrict__ bq2,
    __bf16* __restrict__ qbf, float* __restrict__ q64) {
    const int b = blockIdx.y, tid = threadIdx.x;
    const int o = blockIdx.x * 256 + tid;
    __shared__ float h[DDIM];
    if (tid < DDIM) h[tid] = h_in[b * DDIM + tid];
    __syncthreads();
    if (o >= KQ * DDIM) return;
    float a = bq2[o];
    #pragma unroll 13
    for (int e = 0; e < DDIM; ++e) a += h[e] * Wq2[e * (KQ * DDIM) + o];
    a *= SCALE;
    const int k = o / DDIM, d = o - k * DDIM;
    if (d < 64) qbf[(size_t)b * 4096 + k * 64 + d] = (__bf16)a;
    else        q64[b * 64 + k] = a;
}

// ---------------------------------------------------------------------------
// Kernel 3 (MFMA): per (b, chunk).  In-register softmax; LDS 27.9 KB ->
// 5 blocks/CU.  D=65: MFMA over 64 + fp32 rank-1 fixup; d=64..71 written as
// one aligned 16-B store (o64 + zero pad).
// ---------------------------------------------------------------------------
__global__ __launch_bounds__(256, 5) void k_attn(const float* __restrict__ x,
    const __bf16* __restrict__ qbf, const float* __restrict__ q64,
    const __bf16* __restrict__ WkT, const __bf16* __restrict__ WvT,
    const float* __restrict__ Wk, const float* __restrict__ bkb,
    const float* __restrict__ Wv, const float* __restrict__ bvb,
    const float* __restrict__ pos, const float* __restrict__ cq,
    __bf16* __restrict__ blk_out, float* __restrict__ cs_out) {
    const int nb = blockIdx.x;
    const int b  = blockIdx.y;
    const int tid = threadIdx.x;
    const int lane = tid & 63, w = tid >> 6;
    const int l16 = lane & 15, quad = lane >> 4;

    __shared__ __align__(16) __bf16 xsP[64 * 72];    // x chunk, then P
    __shared__ __align__(16) __bf16 keys[64 * 72];   // [c][d], cols 0..64
    __shared__ __align__(16) __bf16 valsT[64 * 72];  // [d][c], d<64
    __shared__ float vals64[64];                     // vals[c][64] fp32
    __shared__ float xs64[64];                       // x[c][64]

    __bf16* blk_row = blk_out + (size_t)b * BLK_BSTRIDE
                              + (size_t)nb * BLK_CHUNKSTRIDE;

    // ---- phase 1: stage x chunk (div-free, 4 threads per row) ----
    {
        const int c = tid >> 2, g = tid & 3;
        const float* xrow = x + ((size_t)b * NSEQ + (size_t)nb * CHUNK + c) * DDIM;
        __bf16* dst = xsP + c * 72;
        #pragma unroll
        for (int j = 0; j < 16; ++j)
            dst[g + 4 * j] = (__bf16)xrow[g + 4 * j];
        if (g == 0) xs64[c] = xrow[64];
    }
    __syncthreads();

    // ---- phase 2: keys/vals via MFMA (M=c, N=d 5 tiles, K=64) ----
    {
        const __bf16* arow = xsP + (w * 16 + l16) * 72 + quad * 8;
        bf16x8 a0 = *(const bf16x8*)arow;
        bf16x8 a1 = *(const bf16x8*)(arow + 32);
        f32x4 ak[5], av[5];
        const f32x4 z = {0.f, 0.f, 0.f, 0.f};
        #pragma unroll
        for (int nt = 0; nt < 5; ++nt) {
            const __bf16* bkr = WkT + (nt * 16 + l16) * 64 + quad * 8;
            const __bf16* bvr = WvT + (nt * 16 + l16) * 64 + quad * 8;
            ak[nt] = MFMA16(a0, *(const bf16x8*)bkr, z);
            ak[nt] = MFMA16(a1, *(const bf16x8*)(bkr + 32), ak[nt]);
            av[nt] = MFMA16(a0, *(const bf16x8*)bvr, z);
            av[nt] = MFMA16(a1, *(const bf16x8*)(bvr + 32), av[nt]);
        }
        float xe[4];
        #pragma unroll
        for (int r = 0; r < 4; ++r) xe[r] = xs64[w * 16 + quad * 4 + r];
        #pragma unroll
        for (int nt = 0; nt < 5; ++nt) {
            const int d = nt * 16 + l16;
            if (d <= 64) {
                const float wk64d = Wk[64 * DDIM + d];
                const float wv64d = Wv[64 * DDIM + d];
                const float bkd = bkb[d], bvd = bvb[d];
                #pragma unroll
                for (int r = 0; r < 4; ++r) {
                    const int c = w * 16 + quad * 4 + r;
                    const float pv = pos[c * DDIM + d];
                    const float kvv = gelu_tanh(ak[nt][r] + xe[r] * wk64d + bkd) + pv;
                    const float vvv = gelu_tanh(av[nt][r] + xe[r] * wv64d + bvd) + pv;
                    keys[c * 72 + d] = (__bf16)kvv;
                    if (d < 64) valsT[d * 72 + c] = (__bf16)vvv;
                    else        vals64[c] = vvv;
                }
            }
        }
    }
    __syncthreads();

    // ---- phase 3: S = q@keys^T + fixup, in-register softmax, P store,
    //      d=64 output column (+ zero pad cols 65..71, one 16-B store) ----
    float csr[4];
    {
        const __bf16* aq = qbf + (size_t)b * 4096 + (w * 16 + l16) * 64 + quad * 8;
        bf16x8 qa0 = *(const bf16x8*)aq;
        bf16x8 qa1 = *(const bf16x8*)(aq + 32);
        const f32x4 z = {0.f, 0.f, 0.f, 0.f};
        float q64k[4];
        #pragma unroll
        for (int r = 0; r < 4; ++r) q64k[r] = q64[b * 64 + w * 16 + quad * 4 + r];
        float st[4][4];                 // [nt][r]
        #pragma unroll
        for (int nt = 0; nt < 4; ++nt) {
            const __bf16* kb = keys + (nt * 16 + l16) * 72 + quad * 8;
            f32x4 sacc = MFMA16(qa0, *(const bf16x8*)kb, z);
            sacc = MFMA16(qa1, *(const bf16x8*)(kb + 32), sacc);
            const float k64c = (float)keys[(nt * 16 + l16) * 72 + 64];
            #pragma unroll
            for (int r = 0; r < 4; ++r)
                st[nt][r] = fmaf(q64k[r], k64c, sacc[r]) * SCALE;
        }
        float mr[4], sum[4], inv[4];
        #pragma unroll
        for (int r = 0; r < 4; ++r) {
            float m = fmaxf(fmaxf(st[0][r], st[1][r]), fmaxf(st[2][r], st[3][r]));
            m = fmaxf(m, __shfl_xor(m, 1));
            m = fmaxf(m, __shfl_xor(m, 2));
            m = fmaxf(m, __shfl_xor(m, 4));
            m = fmaxf(m, __shfl_xor(m, 8));
            mr[r] = m;
            sum[r] = 0.f;
        }
        #pragma unroll
        for (int nt = 0; nt < 4; ++nt)
            #pragma unroll
            for (int r = 0; r < 4; ++r) {
                st[nt][r] = __expf(st[nt][r] - mr[r]);
                sum[r] += st[nt][r];
            }
        #pragma unroll
        for (int r = 0; r < 4; ++r) {
            float s = sum[r];
            s += __shfl_xor(s, 1);
            s += __shfl_xor(s, 2);
            s += __shfl_xor(s, 4);
            s += __shfl_xor(s, 8);
            inv[r] = __builtin_amdgcn_rcpf(s);
        }
        // store P (bf16) into xsP region (xs dead since phase-2 barrier)
        #pragma unroll
        for (int nt = 0; nt < 4; ++nt)
            #pragma unroll
            for (int r = 0; r < 4; ++r)
                xsP[(w * 16 + quad * 4 + r) * 72 + nt * 16 + l16] =
                    (__bf16)(st[nt][r] * inv[r]);
        // d=64 output column from fp32 P
        float v64l[4];
        #pragma unroll
        for (int nt = 0; nt < 4; ++nt) v64l[nt] = vals64[nt * 16 + l16];
        const float cq64 = cq[64];
        #pragma unroll
        for (int r = 0; r < 4; ++r) {
            float o = st[0][r] * v64l[0];
            o = fmaf(st[1][r], v64l[1], o);
            o = fmaf(st[2][r], v64l[2], o);
            o = fmaf(st[3][r], v64l[3], o);
            o += __shfl_xor(o, 1);
            o += __shfl_xor(o, 2);
            o += __shfl_xor(o, 4);
            o += __shfl_xor(o, 8);
            csr[r] = 0.f;
            if (l16 == 0) {
                const float o64 = o * inv[r];
                const int k = w * 16 + quad * 4 + r;
                bf16x8 v8;
                #pragma unroll
                for (int i2 = 0; i2 < 8; ++i2) v8[i2] = (__bf16)0.0f;
                v8[0] = (__bf16)o64;
                *(bf16x8*)(blk_row + k * BLK_ROWSTRIDE + 64) = v8;
                csr[r] = o64 * cq64;
            }
        }
    }
    __syncthreads();

    // ---- phase 5: blk = P @ vals (M=k, N=d 4 tiles, K=64) + cs ----
    {
        const __bf16* pr = xsP + (w * 16 + l16) * 72 + quad * 8;
        bf16x8 pa0 = *(const bf16x8*)pr;
        bf16x8 pa1 = *(const bf16x8*)(pr + 32);
        const f32x4 z = {0.f, 0.f, 0.f, 0.f};
        #pragma unroll
        for (int nt = 0; nt < 4; ++nt) {
            const __bf16* vb = valsT + (nt * 16 + l16) * 72 + quad * 8;
            f32x4 o = MFMA16(pa0, *(const bf16x8*)vb, z);
            o = MFMA16(pa1, *(const bf16x8*)(vb + 32), o);
            const int d = nt * 16 + l16;
            const float cqd = cq[d];
            #pragma unroll
            for (int r = 0; r < 4; ++r) {
                const int k = w * 16 + quad * 4 + r;
                blk_row[k * BLK_ROWSTRIDE + d] = (__bf16)o[r];
                csr[r] = fmaf(o[r], cqd, csr[r]);
            }
        }
        #pragma unroll
        for (int r = 0; r < 4; ++r) {
            float v = csr[r];
            v += __shfl_xor(v, 1);
            v += __shfl_xor(v, 2);
            v += __shfl_xor(v, 4);
            v += __shfl_xor(v, 8);
            if (l16 == 0) {
                const int k = w * 16 + quad * 4 + r;
                cs_out[((size_t)b * KQ + k) * NBLK + nb] = v * SCALE;
            }
        }
    }
}

// ---------------------------------------------------------------------------
// Kernel 4: cross softmax over nb, weighted sum of blk (bf16x8 vector loads,
// fixed per-thread segment), residual, LayerNorm.  grid 2048.
// ---------------------------------------------------------------------------
__global__ __launch_bounds__(256) void k_cross(
    const __bf16* __restrict__ blk, const float* __restrict__ cs,
    const float* __restrict__ rres, const float* __restrict__ gamma,
    const float* __restrict__ beta, float* __restrict__ out) {
    const int bk_ = blockIdx.x;            // b*64 + k
    const int b = bk_ >> 6, k = bk_ & 63;
    const int tid = threadIdx.x;
    const int w = tid >> 6, lane = tid & 63;

    __shared__ float ew[NBLK];
    __shared__ float wredA[4];
    __shared__ float lred[252][8];
    __shared__ float vv[DDIM];
    __shared__ float stats[2];

    // softmax over cs row (256 chunks, one per thread)
    const float v = cs[(size_t)bk_ * NBLK + tid];
    float m = v;
    for (int off = 32; off; off >>= 1) m = fmaxf(m, __shfl_down(m, off));
    if (lane == 0) wredA[w] = m;
    __syncthreads();
    m = fmaxf(fmaxf(wredA[0], wredA[1]), fmaxf(wredA[2], wredA[3]));
    const float e = __expf(v - m);
    ew[tid] = e;
    float s = e;
    for (int off = 32; off; off >>= 1) s += __shfl_down(s, off);
    __syncthreads();
    if (lane == 0) wredA[w] = s;
    __syncthreads();
    const float inv = 1.0f / (wredA[0] + wredA[1] + wredA[2] + wredA[3]);

    // weighted sum: thread t owns seg = t%9 (d = 8*seg..8*seg+7, fixed),
    // rows r = t/9 + 28*it.  Pad cols 65..71 are zeros -> no masking.
    const int g = tid / 9, seg = tid - g * 9;
    float acc[8] = {0.f, 0.f, 0.f, 0.f, 0.f, 0.f, 0.f, 0.f};
    if (tid < 252) {
        const __bf16* base = blk + (size_t)b * BLK_BSTRIDE
                                 + k * BLK_ROWSTRIDE + seg * 8;
        #pragma unroll 2
        for (int it = 0; it < 10; ++it) {
            const int r = it * 28 + g;
            if (r < NBLK) {
                bf16x8 vx = *(const bf16x8*)(base + (size_t)r * BLK_CHUNKSTRIDE);
                const float wg = ew[r];
                #pragma unroll
                for (int i2 = 0; i2 < 8; ++i2)
                    acc[i2] = fmaf(wg, (float)vx[i2], acc[i2]);
            }
        }
        #pragma unroll
        for (int i2 = 0; i2 < 8; ++i2) lred[tid][i2] = acc[i2];
    }
    __syncthreads();
    if (tid < 72) {
        const int sg = tid >> 3, i2 = tid & 7;
        float a = 0.f;
        #pragma unroll 7
        for (int gg = 0; gg < 28; ++gg) a += lred[gg * 9 + sg][i2];
        const int d = sg * 8 + i2;
        if (d < DDIM) vv[d] = a * inv + rres[b * DDIM + d];
    }
    __syncthreads();
    if (tid < 64) {
        float a  = vv[tid] + (tid == 0 ? vv[64] : 0.f);
        float sq = vv[tid] * vv[tid] + (tid == 0 ? vv[64] * vv[64] : 0.f);
        for (int off = 32; off; off >>= 1) {
            a  += __shfl_down(a, off);
            sq += __shfl_down(sq, off);
        }
        if (tid == 0) {
            const float mu  = a * (1.0f / DDIM);
            const float var = sq * (1.0f / DDIM) - mu * mu;
            stats[0] = mu;
            stats[1] = rsqrtf(var + 1e-5f);
        }
    }
    __syncthreads();
    if (tid < DDIM) {
        out[(size_t)bk_ * DDIM + tid] =
            (vv[tid] - stats[0]) * stats[1] * gamma[tid] + beta[tid];
    }
}

// ---------------------------------------------------------------------------
extern "C" void kernel_launch(void* const* d_in, const int* in_sizes, int n_in,
                              void* d_out, int out_size, void* d_ws, size_t ws_size,
                              hipStream_t stream) {
    const float* x    = (const float*)d_in[0];
    const float* Wq1  = (const float*)d_in[1];
    const float* bq1  = (const float*)d_in[2];
    const float* Wq2  = (const float*)d_in[3];
    const float* bq2  = (const float*)d_in[4];
    const float* Wk   = (const float*)d_in[5];
    const float* bk   = (const float*)d_in[6];
    const float* Wv   = (const float*)d_in[7];
    const float* bv   = (const float*)d_in[8];
    const float* cq   = (const float*)d_in[9];
    const float* pos  = (const float*)d_in[10];
    const float* Wr   = (const float*)d_in[11];
    const float* br   = (const float*)d_in[12];
    const float* gamma= (const float*)d_in[13];
    const float* beta = (const float*)d_in[14];
    float* out = (float*)d_out;

    // workspace layout (byte offsets, all 16-B aligned).
    // partial overlaps blk: partial is dead (consumed by k_qgen1) before
    // k_attn writes blk — stream order guarantees this.
    char* w8 = (char*)d_ws;
    __bf16* blk     = (__bf16*)w8;                   // 75,497,472 B
    float*  partial = (float*)w8;                    // 266,240 B (overlap)
    float*  rres    = (float*)(w8 + 75497472);       // 8320 B
    float*  q64     = (float*)(w8 + 75505792);       // 8192 B
    float*  hbuf    = (float*)(w8 + 75513984);       // 8320 B
    float*  cs      = (float*)(w8 + 75522304);       // 2,097,152 B
    __bf16* qbf     = (__bf16*)(w8 + 77619456);      // 262,144 B
    __bf16* WkT     = (__bf16*)(w8 + 77881600);      // 10,240 B
    __bf16* WvT     = (__bf16*)(w8 + 77891840);      // 10,240 B  (end 77,902,080)

    k_gavg<<<dim3(32, 33), 320, 0, stream>>>(x, partial, Wk, Wv, WkT, WvT);
    k_qgen1<<<BATCH, 256, 0, stream>>>(partial, Wq1, bq1, Wr, br, hbuf, rres);
    k_qgen2<<<dim3(17, BATCH), 256, 0, stream>>>(hbuf, Wq2, bq2, qbf, q64);
    k_attn<<<dim3(NBLK, BATCH), 256, 0, stream>>>(x, qbf, q64, WkT, WvT,
                                                  Wk, bk, Wv, bv, pos, cq,
                                                  blk, cs);
    k_cross<<<BATCH * KQ, 256, 0, stream>>>(blk, cs, rres, gamma, beta, out);
}